// Round 2
// baseline (1683.327 us; speedup 1.0000x reference)
//
#include <hip/hip_runtime.h>
#include <cstdint>
#include <cstddef>

#define D_MODEL 1024
#define D_INNER 2048
#define D_STATE 16
#define SEQ     2048
#define NROWS   4096   // B * SEQ

typedef short short4v __attribute__((ext_vector_type(4)));
typedef short short8v __attribute__((ext_vector_type(8)));
typedef float float4v __attribute__((ext_vector_type(4)));

__device__ __forceinline__ float bf2f(short u) {
  union { unsigned int i; float f; } v;
  v.i = ((unsigned int)(unsigned short)u) << 16;
  return v.f;
}
__device__ __forceinline__ short f2bf(float f) {
  union { float f; unsigned int i; } v; v.f = f;
  unsigned int r = v.i + 0x7FFFu + ((v.i >> 16) & 1u);  // RNE
  return (short)(r >> 16);
}
// dtype-flagged scalar load: f32==1 -> float*, else bf16
__device__ __forceinline__ float lde(const void* p, size_t i, int f32) {
  return f32 ? ((const float*)p)[i] : bf2f(((const short*)p)[i]);
}
__device__ __forceinline__ void async16(short* lds, const short* g) {
  __builtin_amdgcn_global_load_lds(
      (const __attribute__((address_space(1))) unsigned int*)g,
      (__attribute__((address_space(3))) unsigned int*)lds, 16, 0, 0);
}

// -------- dtype probe: low 16 bits of each u32 word of x ----------
// bf16 input: low half is a bf16, exponent bits[14:7] concentrated in [100,150].
// fp32 input: low half is mantissa bits, uniform -> ~20% hit rate.
__global__ __launch_bounds__(64) void probe_kernel(const unsigned int* __restrict__ xw,
                                                   int* __restrict__ flag) {
  int cnt = 0;
  for (int i = threadIdx.x; i < 1024; i += 64) {
    unsigned e = (xw[i] >> 7) & 0xFFu;
    cnt += (e >= 100u && e <= 150u) ? 1 : 0;
  }
  #pragma unroll
  for (int o = 32; o >= 1; o >>= 1) cnt += __shfl_xor(cnt, o);
  if (threadIdx.x == 0) *flag = (cnt < 614) ? 1 : 0;   // 1 => fp32 inputs
}

// -------- convert the 3 big weights to bf16 (or copy) ----------
#define WIN_N  4194304u   // 4096*1024
#define WDT_N  4194304u   // 2048*2048
#define WOUT_N 2097152u   // 1024*2048
__global__ __launch_bounds__(256) void cvt_kernel(
    const void* __restrict__ Win, const void* __restrict__ Wdt,
    const void* __restrict__ Wout, short* __restrict__ dst,
    const int* __restrict__ flag) {
  const int f32 = *flag;
  const size_t i = ((size_t)blockIdx.x * 256 + threadIdx.x) * 8;
  const void* src; size_t off;
  if (i < WIN_N)              { src = Win;  off = i; }
  else if (i < WIN_N + WDT_N) { src = Wdt;  off = i - WIN_N; }
  else                        { src = Wout; off = i - WIN_N - WDT_N; }
  if (f32) {
    const float* s = (const float*)src + off;
    short8v o;
    #pragma unroll
    for (int j = 0; j < 8; ++j) o[j] = f2bf(s[j]);
    *(short8v*)&dst[i] = o;
  } else {
    *(short8v*)&dst[i] = *(const short8v*)((const short*)src + off);
  }
}

// -------- LayerNorm ----------
__global__ __launch_bounds__(256) void ln_kernel(
    const void* __restrict__ x, const void* __restrict__ w,
    const void* __restrict__ bb, short* __restrict__ xn,
    const int* __restrict__ flag) {
  const int f32 = *flag;
  const int row = blockIdx.x;
  const int tid = threadIdx.x;
  float v0, v1, v2, v3;
  if (f32) {
    float4v xv = ((const float4v*)((const float*)x + (size_t)row * D_MODEL))[tid];
    v0 = xv[0]; v1 = xv[1]; v2 = xv[2]; v3 = xv[3];
  } else {
    short4v xv = *(const short4v*)&((const short*)x)[(size_t)row * D_MODEL + tid * 4];
    v0 = bf2f(xv[0]); v1 = bf2f(xv[1]); v2 = bf2f(xv[2]); v3 = bf2f(xv[3]);
  }
  float s = v0 + v1 + v2 + v3;
  float q = v0*v0 + v1*v1 + v2*v2 + v3*v3;
  #pragma unroll
  for (int off = 32; off >= 1; off >>= 1) {
    s += __shfl_xor(s, off);
    q += __shfl_xor(q, off);
  }
  __shared__ float red[8];
  const int wid = tid >> 6;
  if ((tid & 63) == 0) { red[wid] = s; red[4 + wid] = q; }
  __syncthreads();
  s = red[0] + red[1] + red[2] + red[3];
  q = red[4] + red[5] + red[6] + red[7];
  const float mu = s * (1.f / 1024.f);
  const float var = q * (1.f / 1024.f) - mu * mu;
  const float rstd = rsqrtf(var + 1e-5f);
  short4v ov;
  #pragma unroll
  for (int j = 0; j < 4; ++j) {
    const float vj = (j == 0) ? v0 : (j == 1) ? v1 : (j == 2) ? v2 : v3;
    const float o = (vj - mu) * rstd * lde(w, tid * 4 + j, f32) + lde(bb, tid * 4 + j, f32);
    ov[j] = f2bf(o);
  }
  *(short4v*)&xn[(size_t)row * D_MODEL + tid * 4] = ov;
}

// -------- MFMA GEMM: C[m,n] = sum_k A[m,k]*B[n,k]; A row stride lda, B stride K
// MODE 0: bf16 store; MODE 1: softplus(acc+bias[n]) bf16; MODE 2: acc+resid -> dtype-flagged store
template <int MODE>
__global__ __launch_bounds__(256) void gemm_bt(
    const short* __restrict__ A, int lda, const short* __restrict__ B,
    void* __restrict__ Cv, int N, int K, const void* __restrict__ aux,
    const int* __restrict__ flag) {
  __shared__ __align__(16) short As[128 * 32];
  __shared__ __align__(16) short Bs[128 * 32];
  const int f32 = *flag;
  const int tid = threadIdx.x;
  const int bm = blockIdx.y << 7;
  const int bn = blockIdx.x << 7;
  const int wid = tid >> 6;
  const int lane = tid & 63;
  const int wm = (wid >> 1) << 6;
  const int wn = (wid & 1) << 6;

  float4v acc[4][4];
  #pragma unroll
  for (int i = 0; i < 4; ++i)
    #pragma unroll
    for (int j = 0; j < 4; ++j) acc[i][j] = (float4v){0.f, 0.f, 0.f, 0.f};

  const int srow = tid >> 2;
  const int scol = (tid & 3) << 3;
  const short* ga = A + (size_t)(bm + srow) * lda + scol;
  const short* gb = B + (size_t)(bn + srow) * K + scol;
  const size_t astep = (size_t)64 * lda;
  const size_t bstep = (size_t)64 * K;

  const int fr = lane & 15;
  const int fq = (lane >> 4) << 3;

  for (int k0 = 0; k0 < K; k0 += 32) {
    async16(&As[tid * 8], ga + k0);
    async16(&As[2048 + tid * 8], ga + astep + k0);
    async16(&Bs[tid * 8], gb + k0);
    async16(&Bs[2048 + tid * 8], gb + bstep + k0);
    __syncthreads();
    short8v af[4], bfv[4];
    #pragma unroll
    for (int i = 0; i < 4; ++i)
      af[i] = *(const short8v*)&As[(wm + i * 16 + fr) * 32 + fq];
    #pragma unroll
    for (int j = 0; j < 4; ++j)
      bfv[j] = *(const short8v*)&Bs[(wn + j * 16 + fr) * 32 + fq];
    #pragma unroll
    for (int i = 0; i < 4; ++i)
      #pragma unroll
      for (int j = 0; j < 4; ++j)
        acc[i][j] = __builtin_amdgcn_mfma_f32_16x16x32_bf16(af[i], bfv[j], acc[i][j], 0, 0, 0);
    __syncthreads();
  }

  const int er = (lane >> 4) << 2;
  const int ec = lane & 15;
  #pragma unroll
  for (int i = 0; i < 4; ++i) {
    #pragma unroll
    for (int j = 0; j < 4; ++j) {
      const int gcol = bn + wn + j * 16 + ec;
      #pragma unroll
      for (int r = 0; r < 4; ++r) {
        const int grow = bm + wm + i * 16 + er + r;
        const size_t idx = (size_t)grow * N + gcol;
        float v = acc[i][j][r];
        if (MODE == 1) {
          v += lde(aux, gcol, f32);
          v = (v > 15.f) ? v : log1pf(__expf(v));
          ((short*)Cv)[idx] = f2bf(v);
        } else if (MODE == 2) {
          v += lde(aux, idx, f32);
          if (f32) ((float*)Cv)[idx] = v;
          else     ((short*)Cv)[idx] = f2bf(v);
        } else {
          ((short*)Cv)[idx] = f2bf(v);
        }
      }
    }
  }
}

// -------- causal depthwise conv (K=4) + SiLU ----------
__global__ __launch_bounds__(256) void conv_silu(
    const short* __restrict__ xz, const void* __restrict__ cw,
    const void* __restrict__ cb, short* __restrict__ xc,
    const int* __restrict__ flag) {
  const int f32 = *flag;
  const int row = blockIdx.x;
  const int c0 = threadIdx.x << 3;
  const int t = row & (SEQ - 1);
  float wreg[32], acc[8];
  #pragma unroll
  for (int j = 0; j < 8; ++j) {
    acc[j] = lde(cb, c0 + j, f32);
    #pragma unroll
    for (int k = 0; k < 4; ++k) wreg[j * 4 + k] = lde(cw, (size_t)(c0 + j) * 4 + k, f32);
  }
  #pragma unroll
  for (int k = 0; k < 4; ++k) {
    if (t + k - 3 >= 0) {
      const short8v xv = *(const short8v*)&xz[(size_t)(row + k - 3) * 4096 + c0];
      #pragma unroll
      for (int j = 0; j < 8; ++j) acc[j] += bf2f(xv[j]) * wreg[j * 4 + k];
    }
  }
  short8v ov;
  #pragma unroll
  for (int j = 0; j < 8; ++j) {
    const float a = acc[j];
    ov[j] = f2bf(a / (1.f + __expf(-a)));
  }
  *(short8v*)&xc[(size_t)row * D_INNER + c0] = ov;
}

// -------- B/C projections ----------
__global__ __launch_bounds__(256) void bc_kernel(
    const short* __restrict__ xc, const void* __restrict__ WB,
    const void* __restrict__ WC, float* __restrict__ Bm, float* __restrict__ Cm,
    const int* __restrict__ flag) {
  const int f32 = *flag;
  const int tid = threadIdx.x;
  const int n = tid & 31;
  const int row = blockIdx.x * 8 + (tid >> 5);
  const short* xr = &xc[(size_t)row * D_INNER];
  float acc = 0.f;
  if (f32) {
    const float* w = (n < 16) ? (const float*)WB + (size_t)n * D_INNER
                              : (const float*)WC + (size_t)(n - 16) * D_INNER;
    for (int k = 0; k < D_INNER; k += 8) {
      const short8v xv = *(const short8v*)&xr[k];
      const float4v w0 = *(const float4v*)&w[k];
      const float4v w1 = *(const float4v*)&w[k + 4];
      #pragma unroll
      for (int j = 0; j < 4; ++j) acc += bf2f(xv[j]) * w0[j];
      #pragma unroll
      for (int j = 0; j < 4; ++j) acc += bf2f(xv[4 + j]) * w1[j];
    }
  } else {
    const short* w = (n < 16) ? (const short*)WB + (size_t)n * D_INNER
                              : (const short*)WC + (size_t)(n - 16) * D_INNER;
    for (int k = 0; k < D_INNER; k += 8) {
      const short8v xv = *(const short8v*)&xr[k];
      const short8v wv = *(const short8v*)&w[k];
      #pragma unroll
      for (int j = 0; j < 8; ++j) acc += bf2f(xv[j]) * bf2f(wv[j]);
    }
  }
  if (n < 16) Bm[(size_t)row * 16 + n] = acc;
  else        Cm[(size_t)row * 16 + (n - 16)] = acc;
}

// -------- selective scan + gating; y written into x_part half of xz ----------
__global__ __launch_bounds__(256) void scan_kernel(
    const short* __restrict__ dt, const short* __restrict__ xc,
    const float* __restrict__ Bm, const float* __restrict__ Cm,
    short* __restrict__ xzb, const void* __restrict__ A_log,
    const void* __restrict__ Dv, const int* __restrict__ flag) {
  const int f32 = *flag;
  const int tid = threadIdx.x;
  const int gid = blockIdx.x * 16 + (tid >> 4);
  const int b = gid >> 11;
  const int di = gid & 2047;
  const int ds = tid & 15;
  const float Acoef = -__expf(lde(A_log, (size_t)di * 16 + ds, f32));
  const float Dval = lde(Dv, di, f32);
  const size_t rb = (size_t)b * SEQ;
  const short* dtp = dt + rb * D_INNER + di;
  const short* xcp = xc + rb * D_INNER + di;
  const float* Bmp = Bm + rb * 16 + ds;
  const float* Cmp = Cm + rb * 16 + ds;
  const short* zp = xzb + rb * 4096 + 2048 + di;
  short* yp = xzb + rb * 4096 + di;     // overwrite dead x_part slots

  float h = 0.f;
  float dt_n = bf2f(dtp[0]);
  float xc_n = bf2f(xcp[0]);
  float b_n = Bmp[0];
  float c_n = Cmp[0];
  for (int t = 0; t < SEQ; ++t) {
    const float dt_c = dt_n, xc_c = xc_n, b_c = b_n, c_c = c_n;
    if (t + 1 < SEQ) {
      dt_n = bf2f(dtp[(size_t)(t + 1) * D_INNER]);
      xc_n = bf2f(xcp[(size_t)(t + 1) * D_INNER]);
      b_n = Bmp[(size_t)(t + 1) * 16];
      c_n = Cmp[(size_t)(t + 1) * 16];
    }
    const float e = __expf(Acoef * dt_c);
    h = h * e + (xc_c * dt_c) * b_c;
    float p = h * c_c;
    p += __shfl_xor(p, 1);
    p += __shfl_xor(p, 2);
    p += __shfl_xor(p, 4);
    p += __shfl_xor(p, 8);
    if (ds == 0) {
      const float z = bf2f(zp[(size_t)t * 4096]);
      const float sz = z / (1.f + __expf(-z));
      yp[(size_t)t * 4096] = f2bf((p + xc_c * Dval) * sz);
    }
  }
}

// -------- launch ----------
extern "C" void kernel_launch(void* const* d_in, const int* in_sizes, int n_in,
                              void* d_out, int out_size, void* d_ws, size_t ws_size,
                              hipStream_t stream) {
  const void* x      = d_in[0];
  const void* norm_w = d_in[1];
  const void* norm_b = d_in[2];
  const void* W_in   = d_in[3];
  const void* conv_w = d_in[4];
  const void* conv_b = d_in[5];
  const void* W_dt   = d_in[6];
  const void* b_dt   = d_in[7];
  const void* W_B    = d_in[8];
  const void* W_C    = d_in[9];
  const void* Dv     = d_in[10];
  const void* A_log  = d_in[11];
  const void* W_out  = d_in[12];

  char* ws = (char*)d_ws;
  const size_t MB = (size_t)1 << 20;
  short* wcvt = (short*)(ws);                 // 20 MB: W_in | W_dt | W_out (bf16)
  short* wbuf = wcvt;
  short* wdt  = wcvt + WIN_N;
  short* wout = wcvt + WIN_N + WDT_N;
  int*   flag = (int*)(ws + 20 * MB);
  short* xzb  = (short*)(ws + 21 * MB);       // 32 MB [4096 x 4096]
  short* xcv  = (short*)(ws + 53 * MB);       // 16 MB
  short* xn   = (short*)(ws + 69 * MB);       //  8 MB (aliased into dtb slot)
  short* dtb  = (short*)(ws + 69 * MB);       // 16 MB
  float* Bm   = (float*)(ws + 85 * MB);       // 256 KB
  float* Cm   = Bm + (size_t)NROWS * 16;      // 256 KB

  probe_kernel<<<1, 64, 0, stream>>>((const unsigned int*)x, flag);
  cvt_kernel<<<5120, 256, 0, stream>>>(W_in, W_dt, W_out, wcvt, flag);
  ln_kernel<<<NROWS, 256, 0, stream>>>(x, norm_w, norm_b, xn, flag);
  gemm_bt<0><<<dim3(32, 32), 256, 0, stream>>>(xn, 1024, wbuf, xzb, 4096, 1024, nullptr, flag);
  conv_silu<<<NROWS, 256, 0, stream>>>(xzb, conv_w, conv_b, xcv, flag);
  gemm_bt<1><<<dim3(16, 32), 256, 0, stream>>>(xcv, 2048, wdt, dtb, 2048, 2048, b_dt, flag);
  bc_kernel<<<NROWS / 8, 256, 0, stream>>>(xcv, W_B, W_C, Bm, Cm, flag);
  scan_kernel<<<256, 256, 0, stream>>>(dtb, xcv, Bm, Cm, xzb, A_log, Dv, flag);
  gemm_bt<2><<<dim3(8, 32), 256, 0, stream>>>(xzb, 4096, wout, d_out, 1024, 2048, x, flag);
}